// Round 1
// baseline (72.155 us; speedup 1.0000x reference)
//
#include <hip/hip_runtime.h>
#include <hip/hip_bf16.h>

// ModulatedLinear: B=4, S=4096, IN=OUT=MOD=512
// out[t,o] = demod[t,o] * sum_i W[o,i]*s[t,i]*x[t,i] + bias[o]
//   s[t,i]    = sum_m mod[t,m]*mod_w[i,m] + mod_b[i]
//   demod[t,o]= rsqrt(sum_i (W[o,i]*s[t,i])^2 + 1e-8)
//
// Strategy: bf16 MFMA for all three GEMMs (threshold 0.10875 allows it).
//  K0: fp32->bf16 converts (modulation, W, W^2, mod_w)
//  K1: s = modb @ mod_wb^T (NT GEMM) ; epilogue writes xs=bf16(x*s), ss=bf16(s*s)
//  K2: dual GEMM out1 = xs@Wb^T, out2 = ss@W2b^T ; epilogue out1*rsqrt(out2+eps)+bias

#define T_TOK 16384
#define DIM 512

typedef __attribute__((ext_vector_type(4))) float f32x4;
typedef __attribute__((ext_vector_type(8))) short bf16x8;

static __device__ __forceinline__ unsigned short f2bf(float f) {
    union { float f; unsigned int u; } v; v.f = f;
    unsigned int u = v.u;
    u += 0x7fffu + ((u >> 16) & 1u);   // RNE
    return (unsigned short)(u >> 16);
}

// ---------------- K0: converts ----------------
__global__ __launch_bounds__(256) void k0_convert(
    const float* __restrict__ mod, const float* __restrict__ weight,
    const float* __restrict__ mod_w,
    unsigned short* __restrict__ modb, unsigned short* __restrict__ Wb,
    unsigned short* __restrict__ W2b, unsigned short* __restrict__ mwb)
{
    const int NV_MOD = (T_TOK * DIM) / 4;   // 2,097,152 float4s
    const int NV_W   = (DIM * DIM) / 4;     // 65,536
    int idx = blockIdx.x * blockDim.x + threadIdx.x;
    int stride = gridDim.x * blockDim.x;
    for (int i = idx; i < NV_MOD; i += stride) {
        f32x4 v = ((const f32x4*)mod)[i];
        ushort4 o; o.x = f2bf(v[0]); o.y = f2bf(v[1]); o.z = f2bf(v[2]); o.w = f2bf(v[3]);
        ((ushort4*)modb)[i] = o;
    }
    for (int i = idx; i < NV_W; i += stride) {
        f32x4 v = ((const f32x4*)weight)[i];
        ushort4 o;  o.x = f2bf(v[0]); o.y = f2bf(v[1]); o.z = f2bf(v[2]); o.w = f2bf(v[3]);
        ((ushort4*)Wb)[i] = o;
        ushort4 o2; o2.x = f2bf(v[0]*v[0]); o2.y = f2bf(v[1]*v[1]);
                    o2.z = f2bf(v[2]*v[2]); o2.w = f2bf(v[3]*v[3]);
        ((ushort4*)W2b)[i] = o2;
        f32x4 m = ((const f32x4*)mod_w)[i];
        ushort4 o3; o3.x = f2bf(m[0]); o3.y = f2bf(m[1]); o3.z = f2bf(m[2]); o3.w = f2bf(m[3]);
        ((ushort4*)mwb)[i] = o3;
    }
}

// Staging helper idea (inlined below): LDS tile [128 rows][64 cols] bf16 (16KB),
// physical slot = logical slot ^ (row & 7)  (8x 16B slots per 128B row).
// global_load_lds writes linearly (base + lane*16), so we pre-swizzle the
// GLOBAL source address (rule #21: both-sides-or-neither).

// ---------------- K1: s-GEMM + xs/ss epilogue ----------------
__global__ __launch_bounds__(256, 2) void k1_style(
    const unsigned short* __restrict__ modb,   // [T][512] bf16
    const unsigned short* __restrict__ mwb,    // [512][512] bf16 (IN x MOD)
    const float* __restrict__ x,               // [T][512] fp32
    const float* __restrict__ mod_b,           // [512]
    unsigned short* __restrict__ xs,           // [T][512] bf16 out
    unsigned short* __restrict__ ss)           // [T][512] bf16 out
{
    __shared__ unsigned short lA[128 * 64];
    __shared__ unsigned short lB[128 * 64];
    const int tid  = threadIdx.x;
    const int lane = tid & 63;
    const int w    = tid >> 6;
    const int wr   = w >> 1, wc = w & 1;
    const int nbn  = DIM / 128;             // 4
    const int bm   = blockIdx.x / nbn;      // 0..127 token-block
    const int bn   = blockIdx.x % nbn;      // 0..3  feature-block

    const int srow  = lane >> 3;            // 0..7
    const int lslot = (lane & 7) ^ srow;    // pre-swizzled source slot
    const int fr    = lane & 15;
    const int fs    = lane >> 4;

    f32x4 acc[4][4] = {};

    const size_t aBase = (size_t)bm * 128 * DIM;
    const size_t bBase = (size_t)bn * 128 * DIM;

    for (int kb = 0; kb < DIM; kb += 64) {
#pragma unroll
        for (int q = 0; q < 4; ++q) {
            int row = w * 32 + q * 8 + srow;
            const unsigned short* ga = modb + aBase + (size_t)row * DIM + kb + lslot * 8;
            const unsigned short* gb = mwb  + bBase + (size_t)row * DIM + kb + lslot * 8;
            __builtin_amdgcn_global_load_lds(
                (__attribute__((address_space(1))) void*)ga,
                (__attribute__((address_space(3))) void*)(lA + w * 2048 + q * 512), 16, 0, 0);
            __builtin_amdgcn_global_load_lds(
                (__attribute__((address_space(1))) void*)gb,
                (__attribute__((address_space(3))) void*)(lB + w * 2048 + q * 512), 16, 0, 0);
        }
        __syncthreads();   // drains vmcnt -> tiles ready
#pragma unroll
        for (int kk = 0; kk < 64; kk += 32) {
            bf16x8 af[4], bfv[4];
#pragma unroll
            for (int mi = 0; mi < 4; ++mi) {
                int row = wr * 64 + mi * 16 + fr;
                int ps  = ((kk >> 3) + fs) ^ (fr & 7);
                af[mi] = *(const bf16x8*)(lA + row * 64 + ps * 8);
            }
#pragma unroll
            for (int ni = 0; ni < 4; ++ni) {
                int row = wc * 64 + ni * 16 + fr;
                int ps  = ((kk >> 3) + fs) ^ (fr & 7);
                bfv[ni] = *(const bf16x8*)(lB + row * 64 + ps * 8);
            }
#pragma unroll
            for (int mi = 0; mi < 4; ++mi)
#pragma unroll
                for (int ni = 0; ni < 4; ++ni)
                    acc[mi][ni] = __builtin_amdgcn_mfma_f32_16x16x32_bf16(
                        af[mi], bfv[ni], acc[mi][ni], 0, 0, 0);
        }
        __syncthreads();
    }

    // epilogue: s = acc + mod_b[col]; write xs = bf16(x*s), ss = bf16(s*s)
#pragma unroll
    for (int ni = 0; ni < 4; ++ni) {
        int col = bn * 128 + wc * 64 + ni * 16 + fr;
        float mb = mod_b[col];
#pragma unroll
        for (int mi = 0; mi < 4; ++mi) {
#pragma unroll
            for (int j = 0; j < 4; ++j) {
                size_t t = (size_t)bm * 128 + wr * 64 + mi * 16 + fs * 4 + j;
                float sv = acc[mi][ni][j] + mb;
                size_t off = t * DIM + col;
                float xv = x[off];
                xs[off] = f2bf(xv * sv);
                ss[off] = f2bf(sv * sv);
            }
        }
    }
}

// ---------------- K2: dual GEMM + demod epilogue ----------------
__global__ __launch_bounds__(256, 2) void k2_main(
    const unsigned short* __restrict__ xs,   // [T][512] bf16
    const unsigned short* __restrict__ ss,   // [T][512] bf16
    const unsigned short* __restrict__ Wb,   // [512][512] bf16 (OUT x IN)
    const unsigned short* __restrict__ W2b,  // [512][512] bf16
    const float* __restrict__ bias,          // [512]
    float* __restrict__ out)                 // [T][512] fp32
{
    __shared__ unsigned short lXS[128 * 64];
    __shared__ unsigned short lSS[128 * 64];
    __shared__ unsigned short lW [128 * 64];
    __shared__ unsigned short lW2[128 * 64];
    const int tid  = threadIdx.x;
    const int lane = tid & 63;
    const int w    = tid >> 6;
    const int wr   = w >> 1, wc = w & 1;
    const int nbn  = DIM / 128;
    const int bm   = blockIdx.x / nbn;
    const int bn   = blockIdx.x % nbn;

    const int srow  = lane >> 3;
    const int lslot = (lane & 7) ^ srow;
    const int fr    = lane & 15;
    const int fs    = lane >> 4;

    f32x4 a1[4][4] = {};
    f32x4 a2[4][4] = {};

    const size_t aBase = (size_t)bm * 128 * DIM;
    const size_t bBase = (size_t)bn * 128 * DIM;

    for (int kb = 0; kb < DIM; kb += 64) {
#pragma unroll
        for (int q = 0; q < 4; ++q) {
            int row = w * 32 + q * 8 + srow;
            size_t goffA = aBase + (size_t)row * DIM + kb + lslot * 8;
            size_t goffB = bBase + (size_t)row * DIM + kb + lslot * 8;
            unsigned ldso = w * 2048 + q * 512;
            __builtin_amdgcn_global_load_lds(
                (__attribute__((address_space(1))) void*)(xs + goffA),
                (__attribute__((address_space(3))) void*)(lXS + ldso), 16, 0, 0);
            __builtin_amdgcn_global_load_lds(
                (__attribute__((address_space(1))) void*)(ss + goffA),
                (__attribute__((address_space(3))) void*)(lSS + ldso), 16, 0, 0);
            __builtin_amdgcn_global_load_lds(
                (__attribute__((address_space(1))) void*)(Wb + goffB),
                (__attribute__((address_space(3))) void*)(lW + ldso), 16, 0, 0);
            __builtin_amdgcn_global_load_lds(
                (__attribute__((address_space(1))) void*)(W2b + goffB),
                (__attribute__((address_space(3))) void*)(lW2 + ldso), 16, 0, 0);
        }
        __syncthreads();
#pragma unroll
        for (int kk = 0; kk < 64; kk += 32) {
            bf16x8 axs[4], ass[4], bw[4], bw2[4];
#pragma unroll
            for (int mi = 0; mi < 4; ++mi) {
                int row = wr * 64 + mi * 16 + fr;
                int ps  = ((kk >> 3) + fs) ^ (fr & 7);
                axs[mi] = *(const bf16x8*)(lXS + row * 64 + ps * 8);
                ass[mi] = *(const bf16x8*)(lSS + row * 64 + ps * 8);
            }
#pragma unroll
            for (int ni = 0; ni < 4; ++ni) {
                int row = wc * 64 + ni * 16 + fr;
                int ps  = ((kk >> 3) + fs) ^ (fr & 7);
                bw[ni]  = *(const bf16x8*)(lW  + row * 64 + ps * 8);
                bw2[ni] = *(const bf16x8*)(lW2 + row * 64 + ps * 8);
            }
#pragma unroll
            for (int mi = 0; mi < 4; ++mi)
#pragma unroll
                for (int ni = 0; ni < 4; ++ni) {
                    a1[mi][ni] = __builtin_amdgcn_mfma_f32_16x16x32_bf16(
                        axs[mi], bw[ni], a1[mi][ni], 0, 0, 0);
                    a2[mi][ni] = __builtin_amdgcn_mfma_f32_16x16x32_bf16(
                        ass[mi], bw2[ni], a2[mi][ni], 0, 0, 0);
                }
        }
        __syncthreads();
    }

    // epilogue: out = a1 * rsqrt(a2 + eps) + bias
#pragma unroll
    for (int ni = 0; ni < 4; ++ni) {
        int o = bn * 128 + wc * 64 + ni * 16 + fr;
        float bo = bias[o];
#pragma unroll
        for (int mi = 0; mi < 4; ++mi) {
#pragma unroll
            for (int j = 0; j < 4; ++j) {
                size_t t = (size_t)bm * 128 + wr * 64 + mi * 16 + fs * 4 + j;
                float d = rsqrtf(a2[mi][ni][j] + 1e-8f);
                out[t * DIM + o] = a1[mi][ni][j] * d + bo;
            }
        }
    }
}

extern "C" void kernel_launch(void* const* d_in, const int* in_sizes, int n_in,
                              void* d_out, int out_size, void* d_ws, size_t ws_size,
                              hipStream_t stream) {
    const float* x      = (const float*)d_in[0];
    const float* mod    = (const float*)d_in[1];
    const float* weight = (const float*)d_in[2];
    const float* bias   = (const float*)d_in[3];
    const float* mod_w  = (const float*)d_in[4];
    const float* mod_b  = (const float*)d_in[5];
    float* out = (float*)d_out;

    // workspace layout (bytes):
    //   modb: 16,777,216 | xs: 16,777,216 | ss: 16,777,216
    //   Wb: 524,288 | W2b: 524,288 | mwb: 524,288   => ~51.9 MB total
    char* ws = (char*)d_ws;
    unsigned short* modb = (unsigned short*)(ws);
    unsigned short* xs   = (unsigned short*)(ws + (size_t)16777216);
    unsigned short* ssb  = (unsigned short*)(ws + (size_t)2 * 16777216);
    unsigned short* Wb   = (unsigned short*)(ws + (size_t)3 * 16777216);
    unsigned short* W2b  = (unsigned short*)(ws + (size_t)3 * 16777216 + 524288);
    unsigned short* mwb  = (unsigned short*)(ws + (size_t)3 * 16777216 + 2 * 524288);

    hipLaunchKernelGGL(k0_convert, dim3(2048), dim3(256), 0, stream,
                       mod, weight, mod_w, modb, Wb, W2b, mwb);
    hipLaunchKernelGGL(k1_style, dim3(512), dim3(256), 0, stream,
                       modb, mwb, x, mod_b, xs, ssb);
    hipLaunchKernelGGL(k2_main, dim3(512), dim3(256), 0, stream,
                       xs, ssb, Wb, W2b, bias, out);
}

// Round 2
// 61.272 us; speedup vs baseline: 1.1776x; 1.1776x over previous
//
#include <hip/hip_runtime.h>
#include <hip/hip_bf16.h>

// ModulatedLinear: B=4, S=4096, IN=OUT=MOD=512
// out[t,o] = demod[t,o] * sum_i W[o,i]*s[t,i]*x[t,i] + bias[o]
//   s[t,i]    = sum_m mod[t,m]*mod_w[i,m] + mod_b[i]
//   demod[t,o]= rsqrt(sum_i (W[o,i]*s[t,i])^2 + 1e-8)
//
// Strategy: bf16 MFMA for all three GEMMs (threshold 0.10875 allows it).
//  K0: fp32->bf16 converts (modulation, W, W^2, mod_w)
//  K1: s = modb @ mod_wb^T (NT GEMM); epilogue transposes s through LDS,
//      reads x coalesced (float4), writes xs=bf16(x*s), ss=bf16(s*s) as ushort8.
//  K2: dual GEMM out1 = xs@Wb^T, out2 = ss@W2b^T ; epilogue out1*rsqrt(out2+eps)+bias

#define T_TOK 16384
#define DIM 512

typedef __attribute__((ext_vector_type(4))) float f32x4;
typedef __attribute__((ext_vector_type(8))) short bf16x8;

static __device__ __forceinline__ unsigned short f2bf(float f) {
    union { float f; unsigned int u; } v; v.f = f;
    unsigned int u = v.u;
    u += 0x7fffu + ((u >> 16) & 1u);   // RNE
    return (unsigned short)(u >> 16);
}
static __device__ __forceinline__ float bf2f(unsigned short h) {
    union { unsigned int u; float f; } v; v.u = ((unsigned int)h) << 16;
    return v.f;
}

// ---------------- K0: converts ----------------
__global__ __launch_bounds__(256) void k0_convert(
    const float* __restrict__ mod, const float* __restrict__ weight,
    const float* __restrict__ mod_w,
    unsigned short* __restrict__ modb, unsigned short* __restrict__ Wb,
    unsigned short* __restrict__ W2b, unsigned short* __restrict__ mwb)
{
    const int NV_MOD = (T_TOK * DIM) / 4;   // 2,097,152 float4s
    const int NV_W   = (DIM * DIM) / 4;     // 65,536
    int idx = blockIdx.x * blockDim.x + threadIdx.x;
    int stride = gridDim.x * blockDim.x;
    for (int i = idx; i < NV_MOD; i += stride) {
        f32x4 v = ((const f32x4*)mod)[i];
        ushort4 o; o.x = f2bf(v[0]); o.y = f2bf(v[1]); o.z = f2bf(v[2]); o.w = f2bf(v[3]);
        ((ushort4*)modb)[i] = o;
    }
    for (int i = idx; i < NV_W; i += stride) {
        f32x4 v = ((const f32x4*)weight)[i];
        ushort4 o;  o.x = f2bf(v[0]); o.y = f2bf(v[1]); o.z = f2bf(v[2]); o.w = f2bf(v[3]);
        ((ushort4*)Wb)[i] = o;
        ushort4 o2; o2.x = f2bf(v[0]*v[0]); o2.y = f2bf(v[1]*v[1]);
                    o2.z = f2bf(v[2]*v[2]); o2.w = f2bf(v[3]*v[3]);
        ((ushort4*)W2b)[i] = o2;
        f32x4 m = ((const f32x4*)mod_w)[i];
        ushort4 o3; o3.x = f2bf(m[0]); o3.y = f2bf(m[1]); o3.z = f2bf(m[2]); o3.w = f2bf(m[3]);
        ((ushort4*)mwb)[i] = o3;
    }
}

// LDS tile [128 rows][64 cols] bf16 (16KB), physical slot = logical ^ (row & 7)
// (8x 16B slots per 128B row). global_load_lds writes linearly, so the GLOBAL
// source address is pre-swizzled (both-sides-or-neither).

// ---------------- K1: s-GEMM + LDS-transpose epilogue ----------------
__global__ __launch_bounds__(256, 2) void k1_style(
    const unsigned short* __restrict__ modb,   // [T][512] bf16
    const unsigned short* __restrict__ mwb,    // [512][512] bf16 (IN x MOD)
    const float* __restrict__ x,               // [T][512] fp32
    const float* __restrict__ mod_b,           // [512]
    unsigned short* __restrict__ xs,           // [T][512] bf16 out
    unsigned short* __restrict__ ss)           // [T][512] bf16 out
{
    __shared__ union {
        struct { unsigned short A[128 * 64]; unsigned short B[128 * 64]; } stg;
        unsigned short str[128 * 144];   // padded s-transpose buffer (36.9KB)
    } u;
    const int tid  = threadIdx.x;
    const int lane = tid & 63;
    const int w    = tid >> 6;
    const int wr   = w >> 1, wc = w & 1;
    const int nbn  = DIM / 128;             // 4
    const int bm   = blockIdx.x / nbn;      // 0..127 token-block
    const int bn   = blockIdx.x % nbn;      // 0..3  feature-block

    const int srow  = lane >> 3;            // 0..7
    const int lslot = (lane & 7) ^ srow;    // pre-swizzled source slot
    const int fr    = lane & 15;
    const int fs    = lane >> 4;

    f32x4 acc[4][4] = {};

    const size_t aBase = (size_t)bm * 128 * DIM;
    const size_t bBase = (size_t)bn * 128 * DIM;

    for (int kb = 0; kb < DIM; kb += 64) {
#pragma unroll
        for (int q = 0; q < 4; ++q) {
            int row = w * 32 + q * 8 + srow;
            const unsigned short* ga = modb + aBase + (size_t)row * DIM + kb + lslot * 8;
            const unsigned short* gb = mwb  + bBase + (size_t)row * DIM + kb + lslot * 8;
            __builtin_amdgcn_global_load_lds(
                (__attribute__((address_space(1))) void*)ga,
                (__attribute__((address_space(3))) void*)(u.stg.A + w * 2048 + q * 512), 16, 0, 0);
            __builtin_amdgcn_global_load_lds(
                (__attribute__((address_space(1))) void*)gb,
                (__attribute__((address_space(3))) void*)(u.stg.B + w * 2048 + q * 512), 16, 0, 0);
        }
        __syncthreads();   // drains vmcnt -> tiles ready
#pragma unroll
        for (int kk = 0; kk < 64; kk += 32) {
            bf16x8 af[4], bfv[4];
#pragma unroll
            for (int mi = 0; mi < 4; ++mi) {
                int row = wr * 64 + mi * 16 + fr;
                int ps  = ((kk >> 3) + fs) ^ (fr & 7);
                af[mi] = *(const bf16x8*)(u.stg.A + row * 64 + ps * 8);
            }
#pragma unroll
            for (int ni = 0; ni < 4; ++ni) {
                int row = wc * 64 + ni * 16 + fr;
                int ps  = ((kk >> 3) + fs) ^ (fr & 7);
                bfv[ni] = *(const bf16x8*)(u.stg.B + row * 64 + ps * 8);
            }
#pragma unroll
            for (int mi = 0; mi < 4; ++mi)
#pragma unroll
                for (int ni = 0; ni < 4; ++ni)
                    acc[mi][ni] = __builtin_amdgcn_mfma_f32_16x16x32_bf16(
                        af[mi], bfv[ni], acc[mi][ni], 0, 0, 0);
        }
        __syncthreads();
    }

    // ---- epilogue ----
    // 1) scatter s = acc + mod_b as bf16 into padded LDS [128][144]
    //    write banks: 4*(fr>>1) + 8*fs -> all 32 banks, conflict-free
#pragma unroll
    for (int ni = 0; ni < 4; ++ni) {
        int col = wc * 64 + ni * 16 + fr;
        float mb = mod_b[bn * 128 + col];
#pragma unroll
        for (int mi = 0; mi < 4; ++mi) {
#pragma unroll
            for (int j = 0; j < 4; ++j) {
                int row = wr * 64 + mi * 16 + fs * 4 + j;
                u.str[row * 144 + col] = f2bf(acc[mi][ni][j] + mb);
            }
        }
    }
    __syncthreads();
    // 2) read back contiguous per quarter-wave (256B/row slice), load x as
    //    float4 (coalesced), write xs/ss as ushort8 (16B/lane, full lines)
#pragma unroll
    for (int q = 0; q < 8; ++q) {
        int row = w * 32 + q * 4 + (lane >> 4);
        int c8  = (lane & 15) * 8;
        bf16x8 s8 = *(const bf16x8*)(u.str + row * 144 + c8);
        size_t off = ((size_t)bm * 128 + row) * DIM + bn * 128 + c8;
        f32x4 x0 = *(const f32x4*)(x + off);
        f32x4 x1 = *(const f32x4*)(x + off + 4);
        bf16x8 xsv, ssv;
#pragma unroll
        for (int e = 0; e < 8; ++e) {
            float sf = bf2f((unsigned short)s8[e]);
            float xv = (e < 4) ? x0[e] : x1[e - 4];
            xsv[e] = (short)f2bf(xv * sf);
            ssv[e] = (short)f2bf(sf * sf);
        }
        *(bf16x8*)(xs + off) = xsv;
        *(bf16x8*)(ss + off) = ssv;
    }
}

// ---------------- K2: dual GEMM + demod epilogue ----------------
__global__ __launch_bounds__(256, 2) void k2_main(
    const unsigned short* __restrict__ xs,   // [T][512] bf16
    const unsigned short* __restrict__ ss,   // [T][512] bf16
    const unsigned short* __restrict__ Wb,   // [512][512] bf16 (OUT x IN)
    const unsigned short* __restrict__ W2b,  // [512][512] bf16
    const float* __restrict__ bias,          // [512]
    float* __restrict__ out)                 // [T][512] fp32
{
    __shared__ unsigned short lXS[128 * 64];
    __shared__ unsigned short lSS[128 * 64];
    __shared__ unsigned short lW [128 * 64];
    __shared__ unsigned short lW2[128 * 64];
    const int tid  = threadIdx.x;
    const int lane = tid & 63;
    const int w    = tid >> 6;
    const int wr   = w >> 1, wc = w & 1;
    const int nbn  = DIM / 128;
    const int bm   = blockIdx.x / nbn;
    const int bn   = blockIdx.x % nbn;

    const int srow  = lane >> 3;
    const int lslot = (lane & 7) ^ srow;
    const int fr    = lane & 15;
    const int fs    = lane >> 4;

    f32x4 a1[4][4] = {};
    f32x4 a2[4][4] = {};

    const size_t aBase = (size_t)bm * 128 * DIM;
    const size_t bBase = (size_t)bn * 128 * DIM;

    for (int kb = 0; kb < DIM; kb += 64) {
#pragma unroll
        for (int q = 0; q < 4; ++q) {
            int row = w * 32 + q * 8 + srow;
            size_t goffA = aBase + (size_t)row * DIM + kb + lslot * 8;
            size_t goffB = bBase + (size_t)row * DIM + kb + lslot * 8;
            unsigned ldso = w * 2048 + q * 512;
            __builtin_amdgcn_global_load_lds(
                (__attribute__((address_space(1))) void*)(xs + goffA),
                (__attribute__((address_space(3))) void*)(lXS + ldso), 16, 0, 0);
            __builtin_amdgcn_global_load_lds(
                (__attribute__((address_space(1))) void*)(ss + goffA),
                (__attribute__((address_space(3))) void*)(lSS + ldso), 16, 0, 0);
            __builtin_amdgcn_global_load_lds(
                (__attribute__((address_space(1))) void*)(Wb + goffB),
                (__attribute__((address_space(3))) void*)(lW + ldso), 16, 0, 0);
            __builtin_amdgcn_global_load_lds(
                (__attribute__((address_space(1))) void*)(W2b + goffB),
                (__attribute__((address_space(3))) void*)(lW2 + ldso), 16, 0, 0);
        }
        __syncthreads();
#pragma unroll
        for (int kk = 0; kk < 64; kk += 32) {
            bf16x8 axs[4], ass[4], bw[4], bw2[4];
#pragma unroll
            for (int mi = 0; mi < 4; ++mi) {
                int row = wr * 64 + mi * 16 + fr;
                int ps  = ((kk >> 3) + fs) ^ (fr & 7);
                axs[mi] = *(const bf16x8*)(lXS + row * 64 + ps * 8);
                ass[mi] = *(const bf16x8*)(lSS + row * 64 + ps * 8);
            }
#pragma unroll
            for (int ni = 0; ni < 4; ++ni) {
                int row = wc * 64 + ni * 16 + fr;
                int ps  = ((kk >> 3) + fs) ^ (fr & 7);
                bw[ni]  = *(const bf16x8*)(lW  + row * 64 + ps * 8);
                bw2[ni] = *(const bf16x8*)(lW2 + row * 64 + ps * 8);
            }
#pragma unroll
            for (int mi = 0; mi < 4; ++mi)
#pragma unroll
                for (int ni = 0; ni < 4; ++ni) {
                    a1[mi][ni] = __builtin_amdgcn_mfma_f32_16x16x32_bf16(
                        axs[mi], bw[ni], a1[mi][ni], 0, 0, 0);
                    a2[mi][ni] = __builtin_amdgcn_mfma_f32_16x16x32_bf16(
                        ass[mi], bw2[ni], a2[mi][ni], 0, 0, 0);
                }
        }
        __syncthreads();
    }

    // epilogue: out = a1 * rsqrt(a2 + eps) + bias
#pragma unroll
    for (int ni = 0; ni < 4; ++ni) {
        int o = bn * 128 + wc * 64 + ni * 16 + fr;
        float bo = bias[o];
#pragma unroll
        for (int mi = 0; mi < 4; ++mi) {
#pragma unroll
            for (int j = 0; j < 4; ++j) {
                size_t t = (size_t)bm * 128 + wr * 64 + mi * 16 + fs * 4 + j;
                float d = rsqrtf(a2[mi][ni][j] + 1e-8f);
                out[t * DIM + o] = a1[mi][ni][j] * d + bo;
            }
        }
    }
}

extern "C" void kernel_launch(void* const* d_in, const int* in_sizes, int n_in,
                              void* d_out, int out_size, void* d_ws, size_t ws_size,
                              hipStream_t stream) {
    const float* x      = (const float*)d_in[0];
    const float* mod    = (const float*)d_in[1];
    const float* weight = (const float*)d_in[2];
    const float* bias   = (const float*)d_in[3];
    const float* mod_w  = (const float*)d_in[4];
    const float* mod_b  = (const float*)d_in[5];
    float* out = (float*)d_out;

    // workspace layout (bytes):
    //   modb: 16,777,216 | xs: 16,777,216 | ss: 16,777,216
    //   Wb: 524,288 | W2b: 524,288 | mwb: 524,288   => ~51.9 MB total
    char* ws = (char*)d_ws;
    unsigned short* modb = (unsigned short*)(ws);
    unsigned short* xs   = (unsigned short*)(ws + (size_t)16777216);
    unsigned short* ssb  = (unsigned short*)(ws + (size_t)2 * 16777216);
    unsigned short* Wb   = (unsigned short*)(ws + (size_t)3 * 16777216);
    unsigned short* W2b  = (unsigned short*)(ws + (size_t)3 * 16777216 + 524288);
    unsigned short* mwb  = (unsigned short*)(ws + (size_t)3 * 16777216 + 2 * 524288);

    hipLaunchKernelGGL(k0_convert, dim3(2048), dim3(256), 0, stream,
                       mod, weight, mod_w, modb, Wb, W2b, mwb);
    hipLaunchKernelGGL(k1_style, dim3(512), dim3(256), 0, stream,
                       modb, mwb, x, mod_b, xs, ssb);
    hipLaunchKernelGGL(k2_main, dim3(512), dim3(256), 0, stream,
                       xs, ssb, Wb, W2b, bias, out);
}